// Round 6
// baseline (448.108 us; speedup 1.0000x reference)
//
#include <hip/hip_runtime.h>

#define NN 100000
#define NSTEP 5
#define LSTR 264   // ushorts; 528B rows, 16B aligned for ds_read_b128

typedef unsigned short ushort_t;
typedef __attribute__((ext_vector_type(8))) short short8;
typedef __attribute__((ext_vector_type(4))) float floatx4;

__device__ __forceinline__ ushort_t f2bf(float f){
  union { float f; unsigned u; } v; v.f = f;
  unsigned r = v.u + 0x7fffu + ((v.u >> 16) & 1u);
  return (ushort_t)(r >> 16);
}
__device__ __forceinline__ float bf2f(ushort_t s){
  union { unsigned u; float f; } v; v.u = ((unsigned)s) << 16;
  return v.f;
}
__device__ __forceinline__ float sigf(float x){ return 1.0f/(1.0f+__expf(-x)); }

// ================= fused FNN: hfeat = (elu(x@W1+b1))@W2+b2, bf16 out =================
// 1563 blocks x 512 thr (8 waves), 64 rows x 256 cols, 33.8 KB LDS. NO launch-bounds hint
// (R1/R3/R4: hints either no-op at 36 VGPR or regress). Pipelining is forced by DATAFLOW:
// ping-pong fragment buffers (afA/afB, bfA/bfB) make next-kc loads live across the current
// MFMA cluster -> ~95 total regs (4-5 waves/SIMD tier), loads in flight instead of the
// rolled-loop 250cy-serial chain that pinned MfmaUtil at 13%.
__global__ __launch_bounds__(512) void fnn_fused(const float* __restrict__ x,
    const ushort_t* __restrict__ W1P, const float* __restrict__ b1,
    const ushort_t* __restrict__ W2P, const float* __restrict__ b2,
    ushort_t* __restrict__ hfeat, int M)
{
  __shared__ ushort_t buf[64 * LSTR];
  int tid = threadIdx.x;
  int w = tid >> 6, lane = tid & 63, qd = lane >> 4, r16 = lane & 15;
  int row0 = blockIdx.x * 64;
  int col0 = w * 32;

  floatx4 acc[4][2];
  short8 afA[4], afB[4], bfA[2], bfB[2];

  auto LDA = [&](short8* d, int kc){
    #pragma unroll
    for (int i=0;i<4;i++) d[i] = *(const short8*)&buf[(i*16 + r16)*LSTR + kc*32 + qd*8];
  };
  auto LDW = [&](short8* d, const ushort_t* P, int kc){
    #pragma unroll
    for (int j=0;j<2;j++) d[j] = *(const short8*)(P + (size_t)(((w*2 + j)*8 + kc)*64 + lane)*8);
  };
  auto MM = [&](short8* a, short8* b){
    #pragma unroll
    for (int i=0;i<4;i++)
      #pragma unroll
      for (int j=0;j<2;j++)
        acc[i][j] = __builtin_amdgcn_mfma_f32_16x16x32_bf16(a[i], b[j], acc[i][j], 0, 0, 0);
  };

  // ---- stage x tile: issue all 8 loads, then convert (xv dies at the barrier) ----
  {
    float4 xv[8];
    #pragma unroll
    for (int it = 0; it < 8; it++){
      int idx = it * 512 + tid;
      int rg = row0 + (idx >> 6); if (rg >= M) rg = M - 1;
      xv[it] = *(const float4*)(x + (size_t)rg * 256 + (idx & 63) * 4);
    }
    #pragma unroll
    for (int it = 0; it < 8; it++){
      int idx = it * 512 + tid;
      ushort4 pk = make_ushort4(f2bf(xv[it].x), f2bf(xv[it].y), f2bf(xv[it].z), f2bf(xv[it].w));
      *(ushort4*)&buf[(idx >> 6) * LSTR + (idx & 63) * 4] = pk;
    }
  }
  LDW(bfA, W1P, 0);            // W1 kc0 in flight under the barrier
  __syncthreads();

  // ---- GEMM1: ping-pong pipeline ----
  #pragma unroll
  for (int i=0;i<4;i++)
    #pragma unroll
    for (int j=0;j<2;j++) acc[i][j] = (floatx4){0.f,0.f,0.f,0.f};
  LDA(afA, 0);
  #pragma unroll
  for (int kc = 0; kc < 8; kc += 2){
    if (kc + 1 < 8){ LDA(afB, kc+1); LDW(bfB, W1P, kc+1); }
    MM(afA, bfA);
    if (kc + 2 < 8){ LDA(afA, kc+2); LDW(bfA, W1P, kc+2); }
    if (kc + 1 < 8) MM(afB, bfB);
  }
  __syncthreads();

  // ---- ELU -> t tile in same LDS (W2 kc0 issued first, hides L2 latency) ----
  LDW(bfA, W2P, 0);
  #pragma unroll
  for (int i=0;i<4;i++){
    #pragma unroll
    for (int j=0;j<2;j++){
      int col = col0 + j*16 + r16;
      float bb = b1[col];
      #pragma unroll
      for (int rr=0;rr<4;rr++){
        int row = i*16 + qd*4 + rr;
        float v = acc[i][j][rr] + bb;
        v = v > 0.f ? v : (__expf(v) - 1.0f);
        buf[row * LSTR + col] = f2bf(v);
      }
    }
  }
  __syncthreads();

  // ---- GEMM2: ping-pong pipeline ----
  #pragma unroll
  for (int i=0;i<4;i++)
    #pragma unroll
    for (int j=0;j<2;j++) acc[i][j] = (floatx4){0.f,0.f,0.f,0.f};
  LDA(afA, 0);
  #pragma unroll
  for (int kc = 0; kc < 8; kc += 2){
    if (kc + 1 < 8){ LDA(afB, kc+1); LDW(bfB, W2P, kc+1); }
    MM(afA, bfA);
    if (kc + 2 < 8){ LDA(afA, kc+2); LDW(bfA, W2P, kc+2); }
    if (kc + 1 < 8) MM(afB, bfB);
  }

  #pragma unroll
  for (int i=0;i<4;i++){
    #pragma unroll
    for (int j=0;j<2;j++){
      int col = col0 + j*16 + r16;
      float bb = b2[col];
      #pragma unroll
      for (int rr=0;rr<4;rr++){
        int row = row0 + i*16 + qd*4 + rr;
        if (row < M) hfeat[(size_t)row * 256 + col] = f2bf(acc[i][j][rr] + bb);
      }
    }
  }
}

// ================= LSTM layer: gates GEMM (K-split x4 waves) + fused cell =================
// 128 blocks x 256 on 256 CUs: occupancy is irrelevant (<=1 block/CU), so (256,1) gives the
// allocator a 512-reg budget and the compile-time-KC unrolled loop can hoist all loads.
// FIN=true (layer0, steps>=1): fold attn_fin in — sum the 8 attention partials for this
// block's 16 rows into LDS (shr) and read the r-half A-fragments (kc 8..15) from LDS.
template<int KC, bool FIN>
__global__ __launch_bounds__(256, 1) void lstm_layer(const ushort_t* __restrict__ A,
    const ushort_t* __restrict__ WcP, const float* __restrict__ bcp,
    float* __restrict__ c, ushort_t* __restrict__ dstA, int sA,
    ushort_t* __restrict__ dstB, int sB, float* __restrict__ qdst,
    const float* __restrict__ r_part, const float* __restrict__ z_part)
{
  __shared__ float sbuf[3][4][256];
  __shared__ ushort_t shr[16][264];
  constexpr int lda = KC * 32;
  constexpr int kcq = KC >> 2;
  int tid = threadIdx.x, w = tid >> 6, lane = tid & 63, qd = lane >> 4, r16 = lane & 15;
  int m0 = (blockIdx.x & 7) * 16, nt = blockIdx.x >> 3;

  if (FIN){
    int col = tid;
    #pragma unroll 4
    for (int r = 0; r < 16; r++){
      int bb = m0 + r;
      const float* rp = r_part + ((size_t)bb*256 + col)*8;
      float4 aa = *(const float4*)rp;
      float4 ab = *(const float4*)(rp + 4);
      float s = aa.x+aa.y+aa.z+aa.w + ab.x+ab.y+ab.z+ab.w;
      const float* zp = z_part + bb*8;
      float4 za = *(const float4*)zp;
      float4 zb = *(const float4*)(zp + 4);
      float z = za.x+za.y+za.z+za.w + zb.x+zb.y+zb.z+zb.w;
      shr[r][col] = f2bf(s / (z + 1e-16f));
    }
    __syncthreads();
  }

  int kc0 = w * kcq;
  floatx4 acc[4];
  #pragma unroll
  for (int g=0; g<4; g++) acc[g] = (floatx4){0.f,0.f,0.f,0.f};

  const ushort_t* Ar = A + (size_t)(m0 + r16) * lda + qd * 8;
  #pragma unroll
  for (int kk = 0; kk < kcq; kk++){
    int kc = kc0 + kk;
    short8 av;
    if (FIN && kc >= 8 && kc < 16)
      av = *(const short8*)&shr[r16][(kc - 8)*32 + qd*8];
    else
      av = *(const short8*)(Ar + kc*32);
    #pragma unroll
    for (int g = 0; g < 4; g++){
      short8 bv = *(const short8*)(WcP + (size_t)((((g*16 + nt)*KC) + kc)*64 + lane)*8);
      acc[g] = __builtin_amdgcn_mfma_f32_16x16x32_bf16(av, bv, acc[g], 0, 0, 0);
    }
  }
  if (w){
    #pragma unroll
    for (int g=0; g<4; g++) *(floatx4*)&sbuf[w-1][g][lane*4] = acc[g];
  }
  __syncthreads();
  if (w == 0){
    #pragma unroll
    for (int g=0; g<4; g++)
      #pragma unroll
      for (int t=0; t<3; t++){
        floatx4 p = *(floatx4*)&sbuf[t][g][lane*4];
        acc[g] = acc[g] + p;
      }
    int h = nt*16 + r16;
    float bci = bcp[h], bcf = bcp[256+h], bcg = bcp[512+h], bco = bcp[768+h];
    #pragma unroll
    for (int rr=0; rr<4; rr++){
      int row = m0 + qd*4 + rr;
      float gi = acc[0][rr] + bci;
      float gf = acc[1][rr] + bcf;
      float gg = acc[2][rr] + bcg;
      float go = acc[3][rr] + bco;
      float cp = c[row*256 + h];
      float cn = sigf(gf)*cp + sigf(gi)*tanhf(gg);
      float hn = sigf(go)*tanhf(cn);
      c[row*256 + h] = cn;
      ushort_t hb = f2bf(hn);
      dstA[row*sA + h] = hb;
      dstB[row*sB + h] = hb;
      if (qdst) qdst[row*512 + h] = hn;
    }
  }
}

// ================= segment-owned attention: no atomics, no bidx =================
// 1024 blocks x 256 thr; block = (segment b = blockIdx>>3, eighth p = blockIdx&7) via seg[].
// 4 waves, each wave owns nodes (n-q0)%4==w in groups of 4 -> FOUR independent shfl-reduce
// chains per iteration (the 6-deep ds_bpermute chain is the serial core; x4 ILP amortizes
// it), prefetch one group ahead. Partials -> r_part[b][c][8] / z_part[b][8] (read by the
// NEXT lstm0's folded fin prologue; no attn_fin dispatch except the final output).
__global__ __launch_bounds__(256) void attn_onepass(const ushort_t* __restrict__ hfeat,
    const int* __restrict__ seg, const float* __restrict__ q_star,
    float* __restrict__ r_part, float* __restrict__ z_part)
{
  __shared__ float sred[4][260];
  int b = blockIdx.x >> 3, p = blockIdx.x & 7;
  int w = threadIdx.x >> 6, lane = threadIdx.x & 63;
  int s0 = seg[b], s1 = seg[b+1], len = s1 - s0;
  int q0 = s0 + ((len * p) >> 3);
  int q1 = s0 + ((len * (p+1)) >> 3);

  float S0=0.f, S1=0.f, S2=0.f, S3=0.f, Z=0.f;
  float4 q = *(const float4*)(q_star + (size_t)b*512 + lane*4);

  ushort4 cur[4];
  int base = q0 + w;
  #pragma unroll
  for (int u=0;u<4;u++){
    int n = base + 4*u;
    cur[u] = (n < q1) ? *(const ushort4*)(hfeat + (size_t)n*256 + lane*4)
                      : make_ushort4(0,0,0,0);
  }
  for (; base < q1; base += 16){
    ushort4 nxt[4];
    #pragma unroll
    for (int u=0;u<4;u++){
      int n = base + 16 + 4*u;
      nxt[u] = (n < q1) ? *(const ushort4*)(hfeat + (size_t)n*256 + lane*4) : cur[u];
    }
    float fv[4][4], d[4];
    #pragma unroll
    for (int u=0;u<4;u++){
      fv[u][0]=bf2f(cur[u].x); fv[u][1]=bf2f(cur[u].y);
      fv[u][2]=bf2f(cur[u].z); fv[u][3]=bf2f(cur[u].w);
      d[u] = fv[u][0]*q.x + fv[u][1]*q.y + fv[u][2]*q.z + fv[u][3]*q.w;
    }
    #pragma unroll
    for (int off = 32; off; off >>= 1){
      #pragma unroll
      for (int u=0;u<4;u++) d[u] += __shfl_xor(d[u], off);
    }
    #pragma unroll
    for (int u=0;u<4;u++){
      if (base + 4*u < q1){
        float wt = __expf(d[u]);
        Z += wt;
        S0 += wt*fv[u][0]; S1 += wt*fv[u][1];
        S2 += wt*fv[u][2]; S3 += wt*fv[u][3];
      }
    }
    #pragma unroll
    for (int u=0;u<4;u++) cur[u] = nxt[u];
  }

  // block reduce (4 waves) -> one partial store, no atomics
  *(float4*)&sred[w][lane*4] = (float4){S0, S1, S2, S3};
  if (lane == 0) sred[w][256] = Z;
  __syncthreads();
  int f = threadIdx.x;
  if (f < 256){
    float v = sred[0][f] + sred[1][f] + sred[2][f] + sred[3][f];
    r_part[((size_t)b*256 + f)*8 + p] = v;
    if (f == 0)
      z_part[b*8 + p] = sred[0][256] + sred[1][256] + sred[2][256] + sred[3][256];
  }
}

// ================= final output: out = [q | r] @ outW + outb (once, after last attn) =====
__global__ __launch_bounds__(256) void attn_fin(const float* __restrict__ r_part,
    const float* __restrict__ z_part, const float* __restrict__ q_star,
    const float* __restrict__ outW, const float* __restrict__ outb,
    float* __restrict__ out)
{
  __shared__ float qs[512];
  int b = blockIdx.x, f = threadIdx.x;
  const float* rp = r_part + ((size_t)b*256 + f)*8;
  float4 aa = *(const float4*)rp;
  float4 ab = *(const float4*)(rp + 4);
  float s = aa.x+aa.y+aa.z+aa.w + ab.x+ab.y+ab.z+ab.w;
  const float* zp = z_part + b*8;
  float4 za = *(const float4*)zp;
  float4 zb = *(const float4*)(zp + 4);
  float z = za.x+za.y+za.z+za.w + zb.x+zb.y+zb.z+zb.w;
  qs[256 + f] = s / (z + 1e-16f);
  qs[f] = q_star[b*512 + f];     // q half (written by lstm2, prior dispatch)
  __syncthreads();
  if (f < 128){
    float acc = outb[f];
    for (int k = 0; k < 512; k++) acc += qs[k] * outW[k*128 + f];
    out[b*128 + f] = acc;
  }
}

// ================= prep: fragment-major weight packing + all zero/init =================
// Packed layout per 16-col tile T, 32-k chunk kc: [(T*KC + kc)*64 + lane]*8 + j,
// where lane holds BT[n = T*16 + (lane&15)][k = kc*32 + (lane>>4)*8 + j].
__global__ void prep_all(const float* __restrict__ W1, const float* __restrict__ W2,
    const float* __restrict__ Wih0, const float* __restrict__ Whh0,
    const float* __restrict__ Wih1, const float* __restrict__ Whh1,
    const float* __restrict__ Wih2, const float* __restrict__ Whh2,
    const float* __restrict__ bih0, const float* __restrict__ bhh0,
    const float* __restrict__ bih1, const float* __restrict__ bhh1,
    const float* __restrict__ bih2, const float* __restrict__ bhh2,
    const int* __restrict__ bidx,
    ushort_t* __restrict__ W1P, ushort_t* __restrict__ W2P,
    ushort_t* __restrict__ Wc0P, ushort_t* __restrict__ Wc1P, ushort_t* __restrict__ Wc2P,
    float* __restrict__ c, ushort_t* __restrict__ xc, float* __restrict__ q_star,
    float* __restrict__ bc, int* __restrict__ seg)
{
  int i = blockIdx.x*256 + threadIdx.x;
  // --- W1P / W2P: K=256, KC=8, tile size 4096 ---
  if (i < 131072){
    const float* W = (i < 65536) ? W1 : W2;
    ushort_t* P = (i < 65536) ? W1P : W2P;
    int r = i & 65535;
    int T = r >> 12, r2 = r & 4095;
    int kc = r2 >> 9, l = (r2 >> 3) & 63, j = r2 & 7;
    int k = kc*32 + ((l>>4)<<3) + j;
    int n = T*16 + (l & 15);
    P[r] = f2bf(W[k*256 + n]);
    return;
  }
  i -= 131072;
  // --- Wc0P: K=768, KC=24, tile size 12288, 64 tiles ---
  if (i < 786432){
    int T = i / 12288, r2 = i - T*12288;
    int kc = r2 >> 9, l = (r2 >> 3) & 63, j = r2 & 7;
    int k = kc*32 + ((l>>4)<<3) + j;
    int g = T >> 4, n = (T & 15)*16 + (l & 15);
    int row = g*256 + n;
    Wc0P[i] = f2bf(k < 512 ? Wih0[row*512 + k] : Whh0[row*256 + (k - 512)]);
    return;
  }
  i -= 786432;
  // --- Wc1P / Wc2P: K=512, KC=16, tile size 8192, 64 tiles each ---
  if (i < 1048576){
    const float* Wih = (i < 524288) ? Wih1 : Wih2;
    const float* Whh = (i < 524288) ? Whh1 : Whh2;
    ushort_t* P = (i < 524288) ? Wc1P : Wc2P;
    int r = i & 524287;
    int T = r >> 13, r2 = r & 8191;
    int kc = r2 >> 9, l = (r2 >> 3) & 63, j = r2 & 7;
    int k = kc*32 + ((l>>4)<<3) + j;
    int g = T >> 4, n = (T & 15)*16 + (l & 15);
    int row = g*256 + n;
    P[r] = f2bf(k < 256 ? Wih[row*256 + k] : Whh[row*256 + (k - 256)]);
    return;
  }
  i -= 1048576;
  if (i < 98304) { c[i] = 0.f; return; }
  i -= 98304;
  if (i < 229376) { xc[i] = 0; return; }
  i -= 229376;
  if (i < 65536) { q_star[i] = 0.f; return; }
  i -= 65536;
  if (i < 3072) {
    int l = i >> 10, g = i & 1023;
    const float* bi = (l == 0) ? bih0 : ((l == 1) ? bih1 : bih2);
    const float* bh = (l == 0) ? bhh0 : ((l == 1) ? bhh1 : bhh2);
    bc[i] = bi[g] + bh[g];
    return;
  }
  i -= 3072;
  if (i < 129) {
    int lo = 0, hi = NN;
    while (lo < hi){ int mid = (lo + hi) >> 1; if (bidx[mid] < i) lo = mid + 1; else hi = mid; }
    seg[i] = lo;
    return;
  }
}

extern "C" void kernel_launch(void* const* d_in, const int* in_sizes, int n_in,
                              void* d_out, int out_size, void* d_ws, size_t ws_size,
                              hipStream_t stream)
{
  const float* x    = (const float*)d_in[0];
  const int*   bidx = (const int*)  d_in[1];
  const float* W1   = (const float*)d_in[2];
  const float* b1   = (const float*)d_in[3];
  const float* W2   = (const float*)d_in[4];
  const float* b2   = (const float*)d_in[5];
  const float* Wih0 = (const float*)d_in[6];
  const float* Whh0 = (const float*)d_in[7];
  const float* bih0 = (const float*)d_in[8];
  const float* bhh0 = (const float*)d_in[9];
  const float* Wih1 = (const float*)d_in[10];
  const float* Whh1 = (const float*)d_in[11];
  const float* bih1 = (const float*)d_in[12];
  const float* bhh1 = (const float*)d_in[13];
  const float* Wih2 = (const float*)d_in[14];
  const float* Whh2 = (const float*)d_in[15];
  const float* bih2 = (const float*)d_in[16];
  const float* bhh2 = (const float*)d_in[17];
  const float* outW = (const float*)d_in[18];
  const float* outb = (const float*)d_in[19];

  char* p = (char*)d_ws;
  auto alloc = [&](size_t bytes)->char*{ char* r = p; p += (bytes + 255) & ~(size_t)255; return r; };
  ushort_t* hfeat  = (ushort_t*)alloc((size_t)NN*256*2);   // bf16 node features
  ushort_t* W1P    = (ushort_t*)alloc(65536*2);
  ushort_t* W2P    = (ushort_t*)alloc(65536*2);
  ushort_t* Wc0P   = (ushort_t*)alloc(786432*2);
  ushort_t* Wc1P   = (ushort_t*)alloc(524288*2);
  ushort_t* Wc2P   = (ushort_t*)alloc(524288*2);
  float*    bc     = (float*)   alloc(3072*4);
  float*    c_all  = (float*)   alloc(98304*4);
  ushort_t* xc     = (ushort_t*)alloc(229376*2);           // xc0(128x768)|xc1(128x512)|xc2(128x512)
  float*    q_star = (float*)   alloc(65536*4);            // (128,512) fp32; only q-half used
  float*    r_part = (float*)   alloc((size_t)128*256*8*4); // attention partials [b][c][8]
  float*    z_part = (float*)   alloc(128*8*4);             // [b][8]
  int*      seg    = (int*)     alloc(129*4);

  ushort_t* xc0 = xc;
  ushort_t* xc1 = xc + 98304;
  ushort_t* xc2 = xc + 163840;
  float* c0 = c_all, *c1 = c_all + 32768, *c2 = c_all + 65536;
  float* bc0 = bc, *bc1 = bc + 1024, *bc2 = bc + 2048;

  prep_all<<<9229, 256, 0, stream>>>(W1, W2, Wih0, Whh0, Wih1, Whh1, Wih2, Whh2,
                                     bih0, bhh0, bih1, bhh1, bih2, bhh2, bidx,
                                     W1P, W2P, Wc0P, Wc1P, Wc2P,
                                     c_all, xc, q_star, bc, seg);

  fnn_fused<<<1563, 512, 0, stream>>>(x, W1P, b1, W2P, b2, hfeat, NN);

  for (int s = 0; s < NSTEP; s++){
    // layer 0: in = [q | r | h0_prev] (K=768). s>=1 folds the attn finalize (r from
    // partials -> LDS) in; s=0 reads the zero-initialized global r-half.
    if (s == 0)
      lstm_layer<24,false><<<128, 256, 0, stream>>>(xc0, Wc0P, bc0, c0,
          xc0 + 512, 768, xc1, 512, nullptr, nullptr, nullptr);
    else
      lstm_layer<24,true><<<128, 256, 0, stream>>>(xc0, Wc0P, bc0, c0,
          xc0 + 512, 768, xc1, 512, nullptr, r_part, z_part);
    // layer 1: in = [h0 | h1_prev] (K=512)
    lstm_layer<16,false><<<128, 256, 0, stream>>>(xc1, Wc1P, bc1, c1,
        xc1 + 256, 512, xc2, 512, nullptr, nullptr, nullptr);
    // layer 2: in = [h1 | h2_prev] (K=512); h2 = q -> q_star q-half (fp32) + xc0 q-cols
    lstm_layer<16,false><<<128, 256, 0, stream>>>(xc2, Wc2P, bc2, c2,
        xc2 + 256, 512, xc0, 768, q_star, nullptr, nullptr);
    // segment-owned attention partials (consumed by next lstm0 / final fin)
    attn_onepass<<<1024, 256, 0, stream>>>(hfeat, seg, q_star, r_part, z_part);
  }
  attn_fin<<<128, 256, 0, stream>>>(r_part, z_part, q_star, outW, outb, (float*)d_out);
}

// Round 7
// 442.081 us; speedup vs baseline: 1.0136x; 1.0136x over previous
//
#include <hip/hip_runtime.h>

#define NN 100000
#define NSTEP 5
#define LSTR 264   // ushorts; 528B rows, 16B aligned for ds_read_b128

typedef unsigned short ushort_t;
typedef __attribute__((ext_vector_type(8))) short short8;
typedef __attribute__((ext_vector_type(4))) float floatx4;

__device__ __forceinline__ ushort_t f2bf(float f){
  union { float f; unsigned u; } v; v.f = f;
  unsigned r = v.u + 0x7fffu + ((v.u >> 16) & 1u);
  return (ushort_t)(r >> 16);
}
__device__ __forceinline__ float bf2f(ushort_t s){
  union { unsigned u; float f; } v; v.u = ((unsigned)s) << 16;
  return v.f;
}
__device__ __forceinline__ float sigf(float x){ return 1.0f/(1.0f+__expf(-x)); }

// ================= fused FNN: hfeat = (elu(x@W1+b1))@W2+b2, bf16 out =================
// 3125 blocks x 512 thr (8 waves), 32 rows x 256 cols. LDS = 16.5KB x-tile + 32KB weight
// rings = 48.5KB -> 3 blocks/CU = 24 waves/CU.
// Weight pipelining via global_load_lds + counted vmcnt (NO VGPR prefetch: R1/R3/R4/R6
// proved the allocator refuses register pipelining at any hint). Fragment-major chunks are
// per-wave PRIVATE -> no barriers in the pipeline; per-wave FIFO: depth-2 ring, wait
// vmcnt(2) (=1 stage in flight) before consuming kc. lgkmcnt(0) before each STAGE keeps
// the direct-to-LDS write from racing the same-buffer ds_read. M=100000 = 32*3125: no
// row guards anywhere.
__global__ __launch_bounds__(512) void fnn_fused(const float* __restrict__ x,
    const ushort_t* __restrict__ W1P, const float* __restrict__ b1,
    const ushort_t* __restrict__ W2P, const float* __restrict__ b2,
    ushort_t* __restrict__ hfeat, int M)
{
  __shared__ ushort_t buf[32 * LSTR];
  __shared__ ushort_t wst[2][8][2][512];   // [phase][wave][j][1KB chunk]
  int tid = threadIdx.x;
  int w = tid >> 6, lane = tid & 63, qd = lane >> 4, r16 = lane & 15;
  size_t row0 = (size_t)blockIdx.x * 32;

  typedef __attribute__((address_space(3))) unsigned int lds_u32;
  typedef __attribute__((address_space(1))) const unsigned int glb_u32;

  // hoisted biases (complete at the staging barrier -> vmcnt slate clean for the pipeline)
  float bb1[2], bb2[2];
  #pragma unroll
  for (int j = 0; j < 2; j++){
    int col = w*32 + j*16 + r16;
    bb1[j] = b1[col];
    bb2[j] = b2[col];
  }

  // ---- stage x tile (32x256 fp32 -> bf16 LDS) ----
  {
    float4 xv[4];
    #pragma unroll
    for (int it = 0; it < 4; it++){
      int idx = it * 512 + tid;
      xv[it] = *(const float4*)(x + (row0 + (idx >> 6)) * 256 + (idx & 63) * 4);
    }
    #pragma unroll
    for (int it = 0; it < 4; it++){
      int idx = it * 512 + tid;
      ushort4 pk = make_ushort4(f2bf(xv[it].x), f2bf(xv[it].y), f2bf(xv[it].z), f2bf(xv[it].w));
      *(ushort4*)&buf[(idx >> 6) * LSTR + (idx & 63) * 4] = pk;
    }
  }
  __syncthreads();   // x-tile visible; all prior vmem drained (clean FIFO)

  auto STAGE = [&](const ushort_t* __restrict__ P, int kc, int ph){
    #pragma unroll
    for (int j = 0; j < 2; j++){
      const ushort_t* gp = P + (size_t)(((w*2 + j)*8 + kc)*512) + lane*8;
      __builtin_amdgcn_global_load_lds((glb_u32*)gp, (lds_u32*)&wst[ph][w][j][0], 16, 0, 0);
    }
  };

  floatx4 acc[2][2];

  auto GEMM = [&](const ushort_t* __restrict__ P, bool prestaged){
    if (!prestaged){ STAGE(P, 0, 0); STAGE(P, 1, 1); }
    #pragma unroll
    for (int i=0;i<2;i++)
      #pragma unroll
      for (int j=0;j<2;j++) acc[i][j] = (floatx4){0.f,0.f,0.f,0.f};
    #pragma unroll
    for (int kc = 0; kc < 8; kc++){
      int ph = kc & 1;
      if (kc < 7) asm volatile("s_waitcnt vmcnt(2)" ::: "memory");
      else        asm volatile("s_waitcnt vmcnt(0)" ::: "memory");
      short8 af[2], bf[2];
      #pragma unroll
      for (int i=0;i<2;i++)
        af[i] = *(const short8*)&buf[(i*16 + r16)*LSTR + kc*32 + qd*8];
      #pragma unroll
      for (int j=0;j<2;j++)
        bf[j] = *(const short8*)&wst[ph][w][j][lane*8];
      #pragma unroll
      for (int i=0;i<2;i++)
        #pragma unroll
        for (int j=0;j<2;j++)
          acc[i][j] = __builtin_amdgcn_mfma_f32_16x16x32_bf16(af[i], bf[j], acc[i][j], 0, 0, 0);
      if (kc + 2 < 8){
        asm volatile("s_waitcnt lgkmcnt(0)" ::: "memory");  // ring reads done before overwrite
        STAGE(P, kc + 2, ph);
      }
    }
  };

  GEMM(W1P, false);

  // prefetch W2 kc0/1 into the rings; L2 latency hides under ELU (barrier drains = ready)
  asm volatile("s_waitcnt lgkmcnt(0)" ::: "memory");
  STAGE(W2P, 0, 0); STAGE(W2P, 1, 1);
  __syncthreads();   // all GEMM1 buf reads done -> safe to overwrite buf

  // ---- ELU -> t tile in same LDS ----
  #pragma unroll
  for (int i=0;i<2;i++){
    #pragma unroll
    for (int j=0;j<2;j++){
      int col = w*32 + j*16 + r16;
      #pragma unroll
      for (int rr=0;rr<4;rr++){
        int row = i*16 + qd*4 + rr;
        float v = acc[i][j][rr] + bb1[j];
        v = v > 0.f ? v : (__expf(v) - 1.0f);
        buf[row * LSTR + col] = f2bf(v);
      }
    }
  }
  __syncthreads();

  GEMM(W2P, true);

  // ---- epilogue ----
  #pragma unroll
  for (int i=0;i<2;i++){
    #pragma unroll
    for (int j=0;j<2;j++){
      int col = w*32 + j*16 + r16;
      #pragma unroll
      for (int rr=0;rr<4;rr++){
        size_t row = row0 + i*16 + qd*4 + rr;
        hfeat[row * 256 + col] = f2bf(acc[i][j][rr] + bb2[j]);
      }
    }
  }
}

// ================= LSTM layer: gates GEMM (K-split x4 waves) + fused cell =================
// 128 blocks x 256. Plain (256) bounds — R6's (256,1) 512-reg budget regressed the 15
// dispatches ~+40us (likely spill/schedule); reverted. Template KC keeps the loop unrolled.
// FIN=true (layer0, steps>=1): fold attn_fin in — sum the 8 attention partials for this
// block's 16 rows into LDS (shr) and read the r-half A-fragments (kc 8..15) from LDS.
template<int KC, bool FIN>
__global__ __launch_bounds__(256) void lstm_layer(const ushort_t* __restrict__ A,
    const ushort_t* __restrict__ WcP, const float* __restrict__ bcp,
    float* __restrict__ c, ushort_t* __restrict__ dstA, int sA,
    ushort_t* __restrict__ dstB, int sB, float* __restrict__ qdst,
    const float* __restrict__ r_part, const float* __restrict__ z_part)
{
  __shared__ float sbuf[3][4][256];
  __shared__ ushort_t shr[16][264];
  constexpr int lda = KC * 32;
  constexpr int kcq = KC >> 2;
  int tid = threadIdx.x, w = tid >> 6, lane = tid & 63, qd = lane >> 4, r16 = lane & 15;
  int m0 = (blockIdx.x & 7) * 16, nt = blockIdx.x >> 3;

  if (FIN){
    int col = tid;
    #pragma unroll 4
    for (int r = 0; r < 16; r++){
      int bb = m0 + r;
      const float* rp = r_part + ((size_t)bb*256 + col)*8;
      float4 aa = *(const float4*)rp;
      float4 ab = *(const float4*)(rp + 4);
      float s = aa.x+aa.y+aa.z+aa.w + ab.x+ab.y+ab.z+ab.w;
      const float* zp = z_part + bb*8;
      float4 za = *(const float4*)zp;
      float4 zb = *(const float4*)(zp + 4);
      float z = za.x+za.y+za.z+za.w + zb.x+zb.y+zb.z+zb.w;
      shr[r][col] = f2bf(s / (z + 1e-16f));
    }
    __syncthreads();
  }

  int kc0 = w * kcq;
  floatx4 acc[4];
  #pragma unroll
  for (int g=0; g<4; g++) acc[g] = (floatx4){0.f,0.f,0.f,0.f};

  const ushort_t* Ar = A + (size_t)(m0 + r16) * lda + qd * 8;
  #pragma unroll
  for (int kk = 0; kk < kcq; kk++){
    int kc = kc0 + kk;
    short8 av;
    if (FIN && kc >= 8 && kc < 16)
      av = *(const short8*)&shr[r16][(kc - 8)*32 + qd*8];
    else
      av = *(const short8*)(Ar + kc*32);
    #pragma unroll
    for (int g = 0; g < 4; g++){
      short8 bv = *(const short8*)(WcP + (size_t)((((g*16 + nt)*KC) + kc)*64 + lane)*8);
      acc[g] = __builtin_amdgcn_mfma_f32_16x16x32_bf16(av, bv, acc[g], 0, 0, 0);
    }
  }
  if (w){
    #pragma unroll
    for (int g=0; g<4; g++) *(floatx4*)&sbuf[w-1][g][lane*4] = acc[g];
  }
  __syncthreads();
  if (w == 0){
    #pragma unroll
    for (int g=0; g<4; g++)
      #pragma unroll
      for (int t=0; t<3; t++){
        floatx4 p = *(floatx4*)&sbuf[t][g][lane*4];
        acc[g] = acc[g] + p;
      }
    int h = nt*16 + r16;
    float bci = bcp[h], bcf = bcp[256+h], bcg = bcp[512+h], bco = bcp[768+h];
    #pragma unroll
    for (int rr=0; rr<4; rr++){
      int row = m0 + qd*4 + rr;
      float gi = acc[0][rr] + bci;
      float gf = acc[1][rr] + bcf;
      float gg = acc[2][rr] + bcg;
      float go = acc[3][rr] + bco;
      float cp = c[row*256 + h];
      float cn = sigf(gf)*cp + sigf(gi)*tanhf(gg);
      float hn = sigf(go)*tanhf(cn);
      c[row*256 + h] = cn;
      ushort_t hb = f2bf(hn);
      dstA[row*sA + h] = hb;
      dstB[row*sB + h] = hb;
      if (qdst) qdst[row*512 + h] = hn;
    }
  }
}

// ================= segment-owned attention: no atomics, no bidx =================
// 1024 blocks x 256 thr; block = (segment b = blockIdx>>3, eighth p = blockIdx&7) via seg[].
// 4 waves, each wave owns nodes (n-q0)%4==w in groups of 4 -> FOUR independent shfl-reduce
// chains per iteration, prefetch one group ahead. Partials -> r_part[b][c][8] / z_part[b][8]
// (read by the NEXT lstm0's folded fin prologue; final attn_fin does the output GEMM).
__global__ __launch_bounds__(256) void attn_onepass(const ushort_t* __restrict__ hfeat,
    const int* __restrict__ seg, const float* __restrict__ q_star,
    float* __restrict__ r_part, float* __restrict__ z_part)
{
  __shared__ float sred[4][260];
  int b = blockIdx.x >> 3, p = blockIdx.x & 7;
  int w = threadIdx.x >> 6, lane = threadIdx.x & 63;
  int s0 = seg[b], s1 = seg[b+1], len = s1 - s0;
  int q0 = s0 + ((len * p) >> 3);
  int q1 = s0 + ((len * (p+1)) >> 3);

  float S0=0.f, S1=0.f, S2=0.f, S3=0.f, Z=0.f;
  float4 q = *(const float4*)(q_star + (size_t)b*512 + lane*4);

  ushort4 cur[4];
  int base = q0 + w;
  #pragma unroll
  for (int u=0;u<4;u++){
    int n = base + 4*u;
    cur[u] = (n < q1) ? *(const ushort4*)(hfeat + (size_t)n*256 + lane*4)
                      : make_ushort4(0,0,0,0);
  }
  for (; base < q1; base += 16){
    ushort4 nxt[4];
    #pragma unroll
    for (int u=0;u<4;u++){
      int n = base + 16 + 4*u;
      nxt[u] = (n < q1) ? *(const ushort4*)(hfeat + (size_t)n*256 + lane*4) : cur[u];
    }
    float fv[4][4], d[4];
    #pragma unroll
    for (int u=0;u<4;u++){
      fv[u][0]=bf2f(cur[u].x); fv[u][1]=bf2f(cur[u].y);
      fv[u][2]=bf2f(cur[u].z); fv[u][3]=bf2f(cur[u].w);
      d[u] = fv[u][0]*q.x + fv[u][1]*q.y + fv[u][2]*q.z + fv[u][3]*q.w;
    }
    #pragma unroll
    for (int off = 32; off; off >>= 1){
      #pragma unroll
      for (int u=0;u<4;u++) d[u] += __shfl_xor(d[u], off);
    }
    #pragma unroll
    for (int u=0;u<4;u++){
      if (base + 4*u < q1){
        float wt = __expf(d[u]);
        Z += wt;
        S0 += wt*fv[u][0]; S1 += wt*fv[u][1];
        S2 += wt*fv[u][2]; S3 += wt*fv[u][3];
      }
    }
    #pragma unroll
    for (int u=0;u<4;u++) cur[u] = nxt[u];
  }

  // block reduce (4 waves) -> one partial store, no atomics
  *(float4*)&sred[w][lane*4] = (float4){S0, S1, S2, S3};
  if (lane == 0) sred[w][256] = Z;
  __syncthreads();
  int f = threadIdx.x;
  if (f < 256){
    float v = sred[0][f] + sred[1][f] + sred[2][f] + sred[3][f];
    r_part[((size_t)b*256 + f)*8 + p] = v;
    if (f == 0)
      z_part[b*8 + p] = sred[0][256] + sred[1][256] + sred[2][256] + sred[3][256];
  }
}

// ================= final output: out = [q | r] @ outW + outb (once, after last attn) =====
__global__ __launch_bounds__(256) void attn_fin(const float* __restrict__ r_part,
    const float* __restrict__ z_part, const float* __restrict__ q_star,
    const float* __restrict__ outW, const float* __restrict__ outb,
    float* __restrict__ out)
{
  __shared__ float qs[512];
  int b = blockIdx.x, f = threadIdx.x;
  const float* rp = r_part + ((size_t)b*256 + f)*8;
  float4 aa = *(const float4*)rp;
  float4 ab = *(const float4*)(rp + 4);
  float s = aa.x+aa.y+aa.z+aa.w + ab.x+ab.y+ab.z+ab.w;
  const float* zp = z_part + b*8;
  float4 za = *(const float4*)zp;
  float4 zb = *(const float4*)(zp + 4);
  float z = za.x+za.y+za.z+za.w + zb.x+zb.y+zb.z+zb.w;
  qs[256 + f] = s / (z + 1e-16f);
  qs[f] = q_star[b*512 + f];     // q half (written by lstm2, prior dispatch)
  __syncthreads();
  if (f < 128){
    float acc = outb[f];
    for (int k = 0; k < 512; k++) acc += qs[k] * outW[k*128 + f];
    out[b*128 + f] = acc;
  }
}

// ================= prep: fragment-major weight packing + all zero/init =================
// Packed layout per 16-col tile T, 32-k chunk kc: [(T*KC + kc)*64 + lane]*8 + j,
// where lane holds BT[n = T*16 + (lane&15)][k = kc*32 + (lane>>4)*8 + j].
__global__ void prep_all(const float* __restrict__ W1, const float* __restrict__ W2,
    const float* __restrict__ Wih0, const float* __restrict__ Whh0,
    const float* __restrict__ Wih1, const float* __restrict__ Whh1,
    const float* __restrict__ Wih2, const float* __restrict__ Whh2,
    const float* __restrict__ bih0, const float* __restrict__ bhh0,
    const float* __restrict__ bih1, const float* __restrict__ bhh1,
    const float* __restrict__ bih2, const float* __restrict__ bhh2,
    const int* __restrict__ bidx,
    ushort_t* __restrict__ W1P, ushort_t* __restrict__ W2P,
    ushort_t* __restrict__ Wc0P, ushort_t* __restrict__ Wc1P, ushort_t* __restrict__ Wc2P,
    float* __restrict__ c, ushort_t* __restrict__ xc, float* __restrict__ q_star,
    float* __restrict__ bc, int* __restrict__ seg)
{
  int i = blockIdx.x*256 + threadIdx.x;
  // --- W1P / W2P: K=256, KC=8, tile size 4096 ---
  if (i < 131072){
    const float* W = (i < 65536) ? W1 : W2;
    ushort_t* P = (i < 65536) ? W1P : W2P;
    int r = i & 65535;
    int T = r >> 12, r2 = r & 4095;
    int kc = r2 >> 9, l = (r2 >> 3) & 63, j = r2 & 7;
    int k = kc*32 + ((l>>4)<<3) + j;
    int n = T*16 + (l & 15);
    P[r] = f2bf(W[k*256 + n]);
    return;
  }
  i -= 131072;
  // --- Wc0P: K=768, KC=24, tile size 12288, 64 tiles ---
  if (i < 786432){
    int T = i / 12288, r2 = i - T*12288;
    int kc = r2 >> 9, l = (r2 >> 3) & 63, j = r2 & 7;
    int k = kc*32 + ((l>>4)<<3) + j;
    int g = T >> 4, n = (T & 15)*16 + (l & 15);
    int row = g*256 + n;
    Wc0P[i] = f2bf(k < 512 ? Wih0[row*512 + k] : Whh0[row*256 + (k - 512)]);
    return;
  }
  i -= 786432;
  // --- Wc1P / Wc2P: K=512, KC=16, tile size 8192, 64 tiles each ---
  if (i < 1048576){
    const float* Wih = (i < 524288) ? Wih1 : Wih2;
    const float* Whh = (i < 524288) ? Whh1 : Whh2;
    ushort_t* P = (i < 524288) ? Wc1P : Wc2P;
    int r = i & 524287;
    int T = r >> 13, r2 = r & 8191;
    int kc = r2 >> 9, l = (r2 >> 3) & 63, j = r2 & 7;
    int k = kc*32 + ((l>>4)<<3) + j;
    int g = T >> 4, n = (T & 15)*16 + (l & 15);
    int row = g*256 + n;
    P[r] = f2bf(k < 256 ? Wih[row*256 + k] : Whh[row*256 + (k - 256)]);
    return;
  }
  i -= 1048576;
  if (i < 98304) { c[i] = 0.f; return; }
  i -= 98304;
  if (i < 229376) { xc[i] = 0; return; }
  i -= 229376;
  if (i < 65536) { q_star[i] = 0.f; return; }
  i -= 65536;
  if (i < 3072) {
    int l = i >> 10, g = i & 1023;
    const float* bi = (l == 0) ? bih0 : ((l == 1) ? bih1 : bih2);
    const float* bh = (l == 0) ? bhh0 : ((l == 1) ? bhh1 : bhh2);
    bc[i] = bi[g] + bh[g];
    return;
  }
  i -= 3072;
  if (i < 129) {
    int lo = 0, hi = NN;
    while (lo < hi){ int mid = (lo + hi) >> 1; if (bidx[mid] < i) lo = mid + 1; else hi = mid; }
    seg[i] = lo;
    return;
  }
}

extern "C" void kernel_launch(void* const* d_in, const int* in_sizes, int n_in,
                              void* d_out, int out_size, void* d_ws, size_t ws_size,
                              hipStream_t stream)
{
  const float* x    = (const float*)d_in[0];
  const int*   bidx = (const int*)  d_in[1];
  const float* W1   = (const float*)d_in[2];
  const float* b1   = (const float*)d_in[3];
  const float* W2   = (const float*)d_in[4];
  const float* b2   = (const float*)d_in[5];
  const float* Wih0 = (const float*)d_in[6];
  const float* Whh0 = (const float*)d_in[7];
  const float* bih0 = (const float*)d_in[8];
  const float* bhh0 = (const float*)d_in[9];
  const float* Wih1 = (const float*)d_in[10];
  const float* Whh1 = (const float*)d_in[11];
  const float* bih1 = (const float*)d_in[12];
  const float* bhh1 = (const float*)d_in[13];
  const float* Wih2 = (const float*)d_in[14];
  const float* Whh2 = (const float*)d_in[15];
  const float* bih2 = (const float*)d_in[16];
  const float* bhh2 = (const float*)d_in[17];
  const float* outW = (const float*)d_in[18];
  const float* outb = (const float*)d_in[19];

  char* p = (char*)d_ws;
  auto alloc = [&](size_t bytes)->char*{ char* r = p; p += (bytes + 255) & ~(size_t)255; return r; };
  ushort_t* hfeat  = (ushort_t*)alloc((size_t)NN*256*2);   // bf16 node features
  ushort_t* W1P    = (ushort_t*)alloc(65536*2);
  ushort_t* W2P    = (ushort_t*)alloc(65536*2);
  ushort_t* Wc0P   = (ushort_t*)alloc(786432*2);
  ushort_t* Wc1P   = (ushort_t*)alloc(524288*2);
  ushort_t* Wc2P   = (ushort_t*)alloc(524288*2);
  float*    bc     = (float*)   alloc(3072*4);
  float*    c_all  = (float*)   alloc(98304*4);
  ushort_t* xc     = (ushort_t*)alloc(229376*2);           // xc0(128x768)|xc1(128x512)|xc2(128x512)
  float*    q_star = (float*)   alloc(65536*4);            // (128,512) fp32; only q-half used
  float*    r_part = (float*)   alloc((size_t)128*256*8*4); // attention partials [b][c][8]
  float*    z_part = (float*)   alloc(128*8*4);             // [b][8]
  int*      seg    = (int*)     alloc(129*4);

  ushort_t* xc0 = xc;
  ushort_t* xc1 = xc + 98304;
  ushort_t* xc2 = xc + 163840;
  float* c0 = c_all, *c1 = c_all + 32768, *c2 = c_all + 65536;
  float* bc0 = bc, *bc1 = bc + 1024, *bc2 = bc + 2048;

  prep_all<<<9229, 256, 0, stream>>>(W1, W2, Wih0, Whh0, Wih1, Whh1, Wih2, Whh2,
                                     bih0, bhh0, bih1, bhh1, bih2, bhh2, bidx,
                                     W1P, W2P, Wc0P, Wc1P, Wc2P,
                                     c_all, xc, q_star, bc, seg);

  fnn_fused<<<3125, 512, 0, stream>>>(x, W1P, b1, W2P, b2, hfeat, NN);

  for (int s = 0; s < NSTEP; s++){
    // layer 0: in = [q | r | h0_prev] (K=768). s>=1 folds the attn finalize (r from
    // partials -> LDS) in; s=0 reads the zero-initialized global r-half.
    if (s == 0)
      lstm_layer<24,false><<<128, 256, 0, stream>>>(xc0, Wc0P, bc0, c0,
          xc0 + 512, 768, xc1, 512, nullptr, nullptr, nullptr);
    else
      lstm_layer<24,true><<<128, 256, 0, stream>>>(xc0, Wc0P, bc0, c0,
          xc0 + 512, 768, xc1, 512, nullptr, r_part, z_part);
    // layer 1: in = [h0 | h1_prev] (K=512)
    lstm_layer<16,false><<<128, 256, 0, stream>>>(xc1, Wc1P, bc1, c1,
        xc1 + 256, 512, xc2, 512, nullptr, nullptr, nullptr);
    // layer 2: in = [h1 | h2_prev] (K=512); h2 = q -> q_star q-half (fp32) + xc0 q-cols
    lstm_layer<16,false><<<128, 256, 0, stream>>>(xc2, Wc2P, bc2, c2,
        xc2 + 256, 512, xc0, 768, q_star, nullptr, nullptr);
    // segment-owned attention partials (consumed by next lstm0 / final fin)
    attn_onepass<<<1024, 256, 0, stream>>>(hfeat, seg, q_star, r_part, z_part);
  }
  attn_fin<<<128, 256, 0, stream>>>(r_part, z_part, q_star, outW, outb, (float*)d_out);
}

// Round 8
// 408.882 us; speedup vs baseline: 1.0959x; 1.0812x over previous
//
#include <hip/hip_runtime.h>

#define NN 100000
#define NSTEP 5
#define LSTR 264   // ushorts; 528B rows, 16B aligned for ds_read_b128

typedef unsigned short ushort_t;
typedef __attribute__((ext_vector_type(8))) short short8;
typedef __attribute__((ext_vector_type(4))) float floatx4;

__device__ __forceinline__ ushort_t f2bf(float f){
  union { float f; unsigned u; } v; v.f = f;
  unsigned r = v.u + 0x7fffu + ((v.u >> 16) & 1u);
  return (ushort_t)(r >> 16);
}
__device__ __forceinline__ float bf2f(ushort_t s){
  union { unsigned u; float f; } v; v.u = ((unsigned)s) << 16;
  return v.f;
}
__device__ __forceinline__ float sigf(float x){ return 1.0f/(1.0f+__expf(-x)); }

// ================= fused FNN: hfeat = (elu(x@W1+b1))@W2+b2, bf16 out =================
// WEIGHTS-IN-REGISTERS persistent blocks. R0-R7 all pinned at 75-95us because every block
// re-read the full 256KB W1P+W2P from L2 (3125 blocks x 256KB = 800MB = ~23us floor) on
// top of serialized HBM/VALU/MFMA phases. Now: 625 blocks x 512 thr, 5 tiles of 32 rows
// each; each wave's weight slice (32 cols, both GEMMs) = 32 short8 = 128 VGPR, loaded ONCE
// per block. K-loops are pure ds_read+MFMA. x staged issue-early/write-late (T14) through
// a double-buffered LDS tile; t tile in LDS. 2 barriers/tile. (512,2) = 256-reg budget
// (pressure ~185). Weight traffic 800MB -> 160MB.
__global__ __launch_bounds__(512, 2) void fnn_fused(const float* __restrict__ x,
    const ushort_t* __restrict__ W1P, const float* __restrict__ b1,
    const ushort_t* __restrict__ W2P, const float* __restrict__ b2,
    ushort_t* __restrict__ hfeat)
{
  __shared__ ushort_t xbuf[2][32 * LSTR];
  __shared__ ushort_t tbuf[32 * LSTR];
  int tid = threadIdx.x;
  int w = tid >> 6, lane = tid & 63, qd = lane >> 4, r16 = lane & 15;

  // ---- per-wave weight fragments, resident across all 5 tiles ----
  short8 w1r[8][2], w2r[8][2];
  #pragma unroll
  for (int kc = 0; kc < 8; kc++)
    #pragma unroll
    for (int j = 0; j < 2; j++){
      size_t off = (size_t)(((w*2 + j)*8 + kc)*64 + lane)*8;
      w1r[kc][j] = *(const short8*)(W1P + off);
      w2r[kc][j] = *(const short8*)(W2P + off);
    }
  float bb1[2], bb2[2];
  #pragma unroll
  for (int j = 0; j < 2; j++){
    int col = w*32 + j*16 + r16;
    bb1[j] = b1[col];
    bb2[j] = b2[col];
  }

  size_t row0 = (size_t)blockIdx.x * 160;   // 5 tiles x 32 rows; 625*160 = 100000 exact

  float4 xv[4];
  // ---- prologue: stage tile 0 ----
  #pragma unroll
  for (int it = 0; it < 4; it++){
    int idx = it*512 + tid;
    xv[it] = *(const float4*)(x + (row0 + (idx>>6))*256 + (idx&63)*4);
  }
  #pragma unroll
  for (int it = 0; it < 4; it++){
    int idx = it*512 + tid;
    ushort4 pk = make_ushort4(f2bf(xv[it].x), f2bf(xv[it].y), f2bf(xv[it].z), f2bf(xv[it].w));
    *(ushort4*)&xbuf[0][(idx>>6)*LSTR + (idx&63)*4] = pk;
  }
  __syncthreads();

  int cur = 0;
  for (int t = 0; t < 5; t++){
    size_t rowt = row0 + t*32;
    // ---- issue next tile's x loads (drain after K2) ----
    if (t < 4){
      #pragma unroll
      for (int it = 0; it < 4; it++){
        int idx = it*512 + tid;
        xv[it] = *(const float4*)(x + (rowt + 32 + (idx>>6))*256 + (idx&63)*4);
      }
    }

    floatx4 acc[2][2];
    // ---- K1: x @ W1 (weights from registers) ----
    #pragma unroll
    for (int i=0;i<2;i++)
      #pragma unroll
      for (int j=0;j<2;j++) acc[i][j] = (floatx4){0.f,0.f,0.f,0.f};
    #pragma unroll
    for (int kc = 0; kc < 8; kc++){
      short8 af[2];
      #pragma unroll
      for (int i=0;i<2;i++)
        af[i] = *(const short8*)&xbuf[cur][(i*16 + r16)*LSTR + kc*32 + qd*8];
      #pragma unroll
      for (int i=0;i<2;i++)
        #pragma unroll
        for (int j=0;j<2;j++)
          acc[i][j] = __builtin_amdgcn_mfma_f32_16x16x32_bf16(af[i], w1r[kc][j], acc[i][j], 0, 0, 0);
    }

    // ---- ELU + b1 -> t tile in LDS ----
    #pragma unroll
    for (int i=0;i<2;i++){
      #pragma unroll
      for (int j=0;j<2;j++){
        int col = w*32 + j*16 + r16;
        #pragma unroll
        for (int rr=0;rr<4;rr++){
          int row = i*16 + qd*4 + rr;
          float v = acc[i][j][rr] + bb1[j];
          v = v > 0.f ? v : (__expf(v) - 1.0f);
          tbuf[row * LSTR + col] = f2bf(v);
        }
      }
    }
    __syncthreads();   // t tile visible to all waves

    // ---- K2: t @ W2 (weights from registers) ----
    #pragma unroll
    for (int i=0;i<2;i++)
      #pragma unroll
      for (int j=0;j<2;j++) acc[i][j] = (floatx4){0.f,0.f,0.f,0.f};
    #pragma unroll
    for (int kc = 0; kc < 8; kc++){
      short8 af[2];
      #pragma unroll
      for (int i=0;i<2;i++)
        af[i] = *(const short8*)&tbuf[(i*16 + r16)*LSTR + kc*32 + qd*8];
      #pragma unroll
      for (int i=0;i<2;i++)
        #pragma unroll
        for (int j=0;j<2;j++)
          acc[i][j] = __builtin_amdgcn_mfma_f32_16x16x32_bf16(af[i], w2r[kc][j], acc[i][j], 0, 0, 0);
    }

    // ---- epilogue: hfeat store ----
    #pragma unroll
    for (int i=0;i<2;i++){
      #pragma unroll
      for (int j=0;j<2;j++){
        int col = w*32 + j*16 + r16;
        #pragma unroll
        for (int rr=0;rr<4;rr++){
          size_t row = rowt + i*16 + qd*4 + rr;
          hfeat[row * 256 + col] = f2bf(acc[i][j][rr] + bb2[j]);
        }
      }
    }

    // ---- convert + write next x tile ----
    if (t < 4){
      #pragma unroll
      for (int it = 0; it < 4; it++){
        int idx = it*512 + tid;
        ushort4 pk = make_ushort4(f2bf(xv[it].x), f2bf(xv[it].y), f2bf(xv[it].z), f2bf(xv[it].w));
        *(ushort4*)&xbuf[cur^1][(idx>>6)*LSTR + (idx&63)*4] = pk;
      }
    }
    __syncthreads();   // next x tile visible; all tbuf reads done
    cur ^= 1;
  }
}

// ================= LSTM layer: gates GEMM (K-split x4 waves) + fused cell =================
// 128 blocks x 256. Block = (m0 = 16 rows, nt = 16 h-cols) x 4 gates. Weights fragment-major.
// (R4-exact configuration — the measured-best rest structure.)
__global__ __launch_bounds__(256) void lstm_layer(const ushort_t* __restrict__ A, int lda,
    const ushort_t* __restrict__ WcP, const float* __restrict__ bcp, int KC,
    float* __restrict__ c, ushort_t* __restrict__ dstA, int sA,
    ushort_t* __restrict__ dstB, int sB, float* __restrict__ qdst)
{
  __shared__ float sbuf[3][4][256];
  int tid = threadIdx.x, w = tid >> 6, lane = tid & 63, qd = lane >> 4, r16 = lane & 15;
  int m0 = (blockIdx.x & 7) * 16, nt = blockIdx.x >> 3;
  int kcq = KC >> 2;                       // chunks per wave: 6 (K=768) or 4 (K=512)
  int kc0 = w * kcq;

  floatx4 acc[4];
  #pragma unroll
  for (int g=0; g<4; g++) acc[g] = (floatx4){0.f,0.f,0.f,0.f};

  const ushort_t* Ar = A + (size_t)(m0 + r16) * lda + qd * 8;
  for (int kc = kc0; kc < kc0 + kcq; kc++){
    short8 av = *(const short8*)(Ar + kc*32);
    #pragma unroll
    for (int g = 0; g < 4; g++){
      short8 bv = *(const short8*)(WcP + (size_t)((((g*16 + nt)*KC) + kc)*64 + lane)*8);
      acc[g] = __builtin_amdgcn_mfma_f32_16x16x32_bf16(av, bv, acc[g], 0, 0, 0);
    }
  }
  if (w){
    #pragma unroll
    for (int g=0; g<4; g++) *(floatx4*)&sbuf[w-1][g][lane*4] = acc[g];
  }
  __syncthreads();
  if (w == 0){
    #pragma unroll
    for (int g=0; g<4; g++)
      #pragma unroll
      for (int t=0; t<3; t++){
        floatx4 p = *(floatx4*)&sbuf[t][g][lane*4];
        acc[g] = acc[g] + p;
      }
    int h = nt*16 + r16;
    float bci = bcp[h], bcf = bcp[256+h], bcg = bcp[512+h], bco = bcp[768+h];
    #pragma unroll
    for (int rr=0; rr<4; rr++){
      int row = m0 + qd*4 + rr;
      float gi = acc[0][rr] + bci;
      float gf = acc[1][rr] + bcf;
      float gg = acc[2][rr] + bcg;
      float go = acc[3][rr] + bco;
      float cp = c[row*256 + h];
      float cn = sigf(gf)*cp + sigf(gi)*tanhf(gg);
      float hn = sigf(go)*tanhf(cn);
      c[row*256 + h] = cn;
      ushort_t hb = f2bf(hn);
      dstA[row*sA + h] = hb;
      dstB[row*sB + h] = hb;
      if (qdst) qdst[row*512 + h] = hn;
    }
  }
}

// ================= segment-owned attention: no atomics, no bidx (R4-exact) =================
// 1024 blocks x 256 thr; block = (segment b = blockIdx>>3, eighth p = blockIdx&7) via seg[].
// 4 waves node-interleaved, x2 unrolled (two independent shfl chains), depth-2 pair prefetch.
// Per-block partial -> r_part[p][b][256] / z_part[p][b]; fin sums the 8 partials.
__global__ __launch_bounds__(256) void attn_onepass(const ushort_t* __restrict__ hfeat,
    const int* __restrict__ seg, const float* __restrict__ q_star,
    float* __restrict__ r_part, float* __restrict__ z_part)
{
  __shared__ float sred[4][260];
  int b = blockIdx.x >> 3, p = blockIdx.x & 7;
  int w = threadIdx.x >> 6, lane = threadIdx.x & 63;
  int s0 = seg[b], s1 = seg[b+1], len = s1 - s0;
  int q0 = s0 + ((len * p) >> 3);
  int q1 = s0 + ((len * (p+1)) >> 3);

  float S0=0.f, S1=0.f, S2=0.f, S3=0.f, Z=0.f;

  int n = q0 + w;
  if (n < q1){
    float4 q = *(const float4*)(q_star + (size_t)b*512 + lane*4);
    #define LOADH(nn) (*(const ushort4*)(hfeat + (size_t)(nn)*256 + lane*4))
    ushort4 ha = LOADH(n);
    ushort4 hb = ha;
    if (n + 4 < q1) hb = LOADH(n + 4);
    for (; n < q1; n += 8){
      // prefetch next pair (wave-uniform guards)
      ushort4 hc = ha, hd = hb;
      if (n + 8  < q1) hc = LOADH(n + 8);
      if (n + 12 < q1) hd = LOADH(n + 12);
      // two independent dot+reduce chains
      float a0=bf2f(ha.x), a1=bf2f(ha.y), a2=bf2f(ha.z), a3=bf2f(ha.w);
      float da = a0*q.x + a1*q.y + a2*q.z + a3*q.w;
      float b0=0.f,b1=0.f,b2=0.f,b3=0.f, db=0.f;
      int vB = (n + 4) < q1;
      if (vB){
        b0=bf2f(hb.x); b1=bf2f(hb.y); b2=bf2f(hb.z); b3=bf2f(hb.w);
        db = b0*q.x + b1*q.y + b2*q.z + b3*q.w;
      }
      #pragma unroll
      for (int off = 32; off; off >>= 1){
        da += __shfl_xor(da, off);
        db += __shfl_xor(db, off);
      }
      float wa = __expf(da);
      Z += wa; S0 += wa*a0; S1 += wa*a1; S2 += wa*a2; S3 += wa*a3;
      if (vB){
        float wb = __expf(db);
        Z += wb; S0 += wb*b0; S1 += wb*b1; S2 += wb*b2; S3 += wb*b3;
      }
      ha = hc; hb = hd;
    }
    #undef LOADH
  }

  // block reduce (4 waves) -> one partial store, no atomics
  *(float4*)&sred[w][lane*4] = (float4){S0, S1, S2, S3};
  if (lane == 0) sred[w][256] = Z;
  __syncthreads();
  int f = threadIdx.x;
  if (f < 256){
    float v = sred[0][f] + sred[1][f] + sred[2][f] + sred[3][f];
    r_part[((size_t)p*128 + b)*256 + f] = v;
    if (f == 0)
      z_part[p*128 + b] = sred[0][256] + sred[1][256] + sred[2][256] + sred[3][256];
  }
}

// ================= finalize: r = sum(partials)/Z -> q_star/xc0; last: output GEMM =========
__global__ __launch_bounds__(256) void attn_fin(const float* __restrict__ r_part,
    const float* __restrict__ z_part, float* __restrict__ q_star, ushort_t* __restrict__ xc0,
    const float* __restrict__ outW, const float* __restrict__ outb,
    float* __restrict__ out, int last)
{
  __shared__ float qs[512];
  int b = blockIdx.x, f = threadIdx.x;
  float s = 0.f, z = 0.f;
  #pragma unroll
  for (int t = 0; t < 8; t++){
    s += r_part[((size_t)(t*128 + b))*256 + f];
    z += z_part[t*128 + b];
  }
  float v = s / (z + 1e-16f);
  q_star[b*512 + 256 + f] = v;
  xc0[b*768 + 256 + f] = f2bf(v);
  if (last){
    qs[f] = q_star[b*512 + f];     // q half (written by lstm2, prior dispatch)
    qs[256 + f] = v;               // r half (computed here)
    __syncthreads();
    if (f < 128){
      float acc = outb[f];
      for (int k = 0; k < 512; k++) acc += qs[k] * outW[k*128 + f];
      out[b*128 + f] = acc;
    }
  }
}

// ================= prep: fragment-major weight packing + all zero/init =================
// Packed layout per 16-col tile T, 32-k chunk kc: [(T*KC + kc)*64 + lane]*8 + j,
// where lane holds BT[n = T*16 + (lane&15)][k = kc*32 + (lane>>4)*8 + j].
__global__ void prep_all(const float* __restrict__ W1, const float* __restrict__ W2,
    const float* __restrict__ Wih0, const float* __restrict__ Whh0,
    const float* __restrict__ Wih1, const float* __restrict__ Whh1,
    const float* __restrict__ Wih2, const float* __restrict__ Whh2,
    const float* __restrict__ bih0, const float* __restrict__ bhh0,
    const float* __restrict__ bih1, const float* __restrict__ bhh1,
    const float* __restrict__ bih2, const float* __restrict__ bhh2,
    const int* __restrict__ bidx,
    ushort_t* __restrict__ W1P, ushort_t* __restrict__ W2P,
    ushort_t* __restrict__ Wc0P, ushort_t* __restrict__ Wc1P, ushort_t* __restrict__ Wc2P,
    float* __restrict__ c, ushort_t* __restrict__ xc, float* __restrict__ q_star,
    float* __restrict__ bc, int* __restrict__ seg)
{
  int i = blockIdx.x*256 + threadIdx.x;
  // --- W1P / W2P: K=256, KC=8, tile size 4096 ---
  if (i < 131072){
    const float* W = (i < 65536) ? W1 : W2;
    ushort_t* P = (i < 65536) ? W1P : W2P;
    int r = i & 65535;
    int T = r >> 12, r2 = r & 4095;
    int kc = r2 >> 9, l = (r2 >> 3) & 63, j = r2 & 7;
    int k = kc*32 + ((l>>4)<<3) + j;
    int n = T*16 + (l & 15);
    P[r] = f2bf(W[k*256 + n]);
    return;
  }
  i -= 131072;
  // --- Wc0P: K=768, KC=24, tile size 12288, 64 tiles ---
  if (i < 786432){
    int T = i / 12288, r2 = i - T*12288;
    int kc = r2 >> 9, l = (r2 >> 3) & 63, j = r2 & 7;
    int k = kc*32 + ((l>>4)<<3) + j;
    int g = T >> 4, n = (T & 15)*16 + (l & 15);
    int row = g*256 + n;
    Wc0P[i] = f2bf(k < 512 ? Wih0[row*512 + k] : Whh0[row*256 + (k - 512)]);
    return;
  }
  i -= 786432;
  // --- Wc1P / Wc2P: K=512, KC=16, tile size 8192, 64 tiles each ---
  if (i < 1048576){
    const float* Wih = (i < 524288) ? Wih1 : Wih2;
    const float* Whh = (i < 524288) ? Whh1 : Whh2;
    ushort_t* P = (i < 524288) ? Wc1P : Wc2P;
    int r = i & 524287;
    int T = r >> 13, r2 = r & 8191;
    int kc = r2 >> 9, l = (r2 >> 3) & 63, j = r2 & 7;
    int k = kc*32 + ((l>>4)<<3) + j;
    int g = T >> 4, n = (T & 15)*16 + (l & 15);
    int row = g*256 + n;
    P[r] = f2bf(k < 256 ? Wih[row*256 + k] : Whh[row*256 + (k - 256)]);
    return;
  }
  i -= 1048576;
  if (i < 98304) { c[i] = 0.f; return; }
  i -= 98304;
  if (i < 229376) { xc[i] = 0; return; }
  i -= 229376;
  if (i < 65536) { q_star[i] = 0.f; return; }
  i -= 65536;
  if (i < 3072) {
    int l = i >> 10, g = i & 1023;
    const float* bi = (l == 0) ? bih0 : ((l == 1) ? bih1 : bih2);
    const float* bh = (l == 0) ? bhh0 : ((l == 1) ? bhh1 : bhh2);
    bc[i] = bi[g] + bh[g];
    return;
  }
  i -= 3072;
  if (i < 129) {
    int lo = 0, hi = NN;
    while (lo < hi){ int mid = (lo + hi) >> 1; if (bidx[mid] < i) lo = mid + 1; else hi = mid; }
    seg[i] = lo;
    return;
  }
}

extern "C" void kernel_launch(void* const* d_in, const int* in_sizes, int n_in,
                              void* d_out, int out_size, void* d_ws, size_t ws_size,
                              hipStream_t stream)
{
  const float* x    = (const float*)d_in[0];
  const int*   bidx = (const int*)  d_in[1];
  const float* W1   = (const float*)d_in[2];
  const float* b1   = (const float*)d_in[3];
  const float* W2   = (const float*)d_in[4];
  const float* b2   = (const float*)d_in[5];
  const float* Wih0 = (const float*)d_in[6];
  const float* Whh0 = (const float*)d_in[7];
  const float* bih0 = (const float*)d_in[8];
  const float* bhh0 = (const float*)d_in[9];
  const float* Wih1 = (const float*)d_in[10];
  const float* Whh1 = (const float*)d_in[11];
  const float* bih1 = (const float*)d_in[12];
  const float* bhh1 = (const float*)d_in[13];
  const float* Wih2 = (const float*)d_in[14];
  const float* Whh2 = (const float*)d_in[15];
  const float* bih2 = (const float*)d_in[16];
  const float* bhh2 = (const float*)d_in[17];
  const float* outW = (const float*)d_in[18];
  const float* outb = (const float*)d_in[19];

  char* p = (char*)d_ws;
  auto alloc = [&](size_t bytes)->char*{ char* r = p; p += (bytes + 255) & ~(size_t)255; return r; };
  ushort_t* hfeat  = (ushort_t*)alloc((size_t)NN*256*2);   // bf16 node features
  ushort_t* W1P    = (ushort_t*)alloc(65536*2);
  ushort_t* W2P    = (ushort_t*)alloc(65536*2);
  ushort_t* Wc0P   = (ushort_t*)alloc(786432*2);
  ushort_t* Wc1P   = (ushort_t*)alloc(524288*2);
  ushort_t* Wc2P   = (ushort_t*)alloc(524288*2);
  float*    bc     = (float*)   alloc(3072*4);
  float*    c_all  = (float*)   alloc(98304*4);
  ushort_t* xc     = (ushort_t*)alloc(229376*2);           // xc0(128x768)|xc1(128x512)|xc2(128x512)
  float*    q_star = (float*)   alloc(65536*4);            // (128,512) fp32
  float*    r_part = (float*)   alloc(8*128*256*4);        // per-eighth attention partials
  float*    z_part = (float*)   alloc(8*128*4);
  int*      seg    = (int*)     alloc(129*4);

  ushort_t* xc0 = xc;
  ushort_t* xc1 = xc + 98304;
  ushort_t* xc2 = xc + 163840;
  float* c0 = c_all, *c1 = c_all + 32768, *c2 = c_all + 65536;
  float* bc0 = bc, *bc1 = bc + 1024, *bc2 = bc + 2048;

  prep_all<<<9229, 256, 0, stream>>>(W1, W2, Wih0, Whh0, Wih1, Whh1, Wih2, Whh2,
                                     bih0, bhh0, bih1, bhh1, bih2, bhh2, bidx,
                                     W1P, W2P, Wc0P, Wc1P, Wc2P,
                                     c_all, xc, q_star, bc, seg);

  fnn_fused<<<625, 512, 0, stream>>>(x, W1P, b1, W2P, b2, hfeat);

  for (int s = 0; s < NSTEP; s++){
    // layer 0: in = [q_star | h0_prev] (K=768, KC=24)
    lstm_layer<<<128, 256, 0, stream>>>(xc0, 768, Wc0P, bc0, 24, c0, xc0 + 512, 768, xc1, 512, nullptr);
    // layer 1: in = [h0 | h1_prev] (K=512, KC=16)
    lstm_layer<<<128, 256, 0, stream>>>(xc1, 512, Wc1P, bc1, 16, c1, xc1 + 256, 512, xc2, 512, nullptr);
    // layer 2: in = [h1 | h2_prev] (K=512); h2 = q
    lstm_layer<<<128, 256, 0, stream>>>(xc2, 512, Wc2P, bc2, 16, c2, xc2 + 256, 512, xc0, 768, q_star);
    // segment-owned attention + finalize (last step folds in the output GEMM)
    attn_onepass<<<1024, 256, 0, stream>>>(hfeat, seg, q_star, r_part, z_part);
    attn_fin<<<128, 256, 0, stream>>>(r_part, z_part, q_star, xc0, outW, outb,
                                      (float*)d_out, s == NSTEP-1 ? 1 : 0);
  }
}